// Round 6
// baseline (131.498 us; speedup 1.0000x reference)
//
#include <hip/hip_runtime.h>
#include <hip/hip_bf16.h>

#define BB 32
#define CC 128
#define OO 128
#define HH 56
#define WW 56
#define KK 4
#define HW 3136
#define WPLANE 147456
#define EPSV 1e-5f

#define NPOS2 232                 // 4 rows x 58 cols staged
#define CHBYTES (NPOS2 * 64)      // byte stride per 32-ch chunk = 14848
// total LDS = 4 chunks * 14848 = 59392 B

typedef __attribute__((ext_vector_type(8))) short short8v;
typedef __attribute__((ext_vector_type(4))) float f32x4;

// ---- convert x -> bf16 channel-last [b][h][w][c], + per-(b,h,c) row sums ----
__global__ void convert_pool_kernel(const float* __restrict__ x,
                                    ushort* __restrict__ xbf,
                                    float* __restrict__ pooledp) {
    const int h = blockIdx.x, b = blockIdx.y;
    __shared__ float xl[128 * 57];
    const float* xp = x + (size_t)(b * CC) * HW + h * WW;
    #pragma unroll
    for (int k = 0; k < 28; ++k) {
        int e = threadIdx.x + k * 256;          // 7168 elems
        int c = e / 56, w = e - c * 56;
        xl[c * 57 + w] = xp[(size_t)c * HW + w];
    }
    __syncthreads();
    ushort* op = xbf + ((size_t)(b * HH + h)) * WW * CC;
    #pragma unroll
    for (int k = 0; k < 7; ++k) {
        int f = threadIdx.x + k * 256;          // 1792 ushort4 units
        int w = f >> 5, c4 = (f & 31) * 4;
        ushort4 v;
        __hip_bfloat16 b0 = __float2bfloat16(xl[(c4 + 0) * 57 + w]);
        __hip_bfloat16 b1 = __float2bfloat16(xl[(c4 + 1) * 57 + w]);
        __hip_bfloat16 b2 = __float2bfloat16(xl[(c4 + 2) * 57 + w]);
        __hip_bfloat16 b3 = __float2bfloat16(xl[(c4 + 3) * 57 + w]);
        v.x = *(ushort*)&b0; v.y = *(ushort*)&b1;
        v.z = *(ushort*)&b2; v.w = *(ushort*)&b3;
        *(ushort4*)(op + (size_t)w * CC + c4) = v;
    }
    if (threadIdx.x < 128) {
        int c = threadIdx.x;
        float s = 0.f;
        #pragma unroll
        for (int w = 0; w < 56; ++w) s += xl[c * 57 + w];
        pooledp[((size_t)(b * HH + h)) * CC + c] = s;
    }
}

// ---- attention: reduce pooled partials + tiny MLP + softmax. block per b ----
__global__ void attn_kernel(const float* __restrict__ pooledp,
                            const float* __restrict__ fc1_w, const float* __restrict__ fc1_b,
                            const float* __restrict__ fc2_w, const float* __restrict__ fc2_b,
                            float* __restrict__ attn) {
    const int b = blockIdx.x, c = threadIdx.x;      // 128 threads
    float s = 0.f;
    for (int h = 0; h < HH; ++h) s += pooledp[((size_t)(b * HH + h)) * CC + c];
    const float pc = s * (1.0f / HW);
    __shared__ float red[8];
    const int lane = c & 63, wid = c >> 6;
    #pragma unroll
    for (int k = 0; k < KK; ++k) {
        float v = pc * fc1_w[k * CC + c];
        for (int off = 32; off > 0; off >>= 1) v += __shfl_down(v, off, 64);
        if (lane == 0) red[k * 2 + wid] = v;
    }
    __syncthreads();
    if (c == 0) {
        float hk[KK], z[KK], m = -1e30f, den = 0.f;
        #pragma unroll
        for (int k = 0; k < KK; ++k)
            hk[k] = fmaxf(red[k * 2] + red[k * 2 + 1] + fc1_b[k], 0.f);
        #pragma unroll
        for (int k = 0; k < KK; ++k) {
            float t = fc2_b[k];
            #pragma unroll
            for (int j = 0; j < KK; ++j) t += hk[j] * fc2_w[k * KK + j];
            z[k] = t; m = fmaxf(m, t);
        }
        #pragma unroll
        for (int k = 0; k < KK; ++k) { z[k] = expf(z[k] - m); den += z[k]; }
        #pragma unroll
        for (int k = 0; k < KK; ++k) attn[b * KK + k] = z[k] / den;
    }
}

// ---- agg_w[b][j][o][c] (bf16) + fused agg_b ----
__global__ void aggw_kernel(const float* __restrict__ attn, const float* __restrict__ weight,
                            const float* __restrict__ bias,
                            ushort* __restrict__ aggw, float* __restrict__ agg_b) {
    int idx = blockIdx.x * 256 + threadIdx.x;
    if (idx < BB * 9 * OO * CC) {
        int c = idx & 127;
        int t = idx >> 7;
        int o = t & 127;
        t >>= 7;
        int j = t % 9;
        int b = t / 9;
        size_t wi = ((size_t)(o * CC + c)) * 9 + j;
        float s = attn[b*KK + 0] * weight[wi]
                + attn[b*KK + 1] * weight[wi + (size_t)WPLANE]
                + attn[b*KK + 2] * weight[wi + (size_t)2*WPLANE]
                + attn[b*KK + 3] * weight[wi + (size_t)3*WPLANE];
        __hip_bfloat16 hb = __float2bfloat16(s);
        aggw[idx] = *(ushort*)&hb;
    }
    if (blockIdx.x < 16) {
        int i = blockIdx.x * 256 + threadIdx.x;   // 0..4095
        int b = i >> 7, o = i & 127;
        float s = 0.f;
        #pragma unroll
        for (int k = 0; k < KK; ++k) s += attn[b*KK + k] * bias[k*OO + o];
        agg_b[i] = s;
    }
}

// ---- implicit-GEMM conv: 896 blocks, 4 waves (o-half x K-half),
//      single-shot swizzled LDS stage, barrier-free K-loop, LDS K-reduction ----
__launch_bounds__(256, 2)
__global__ void conv_kernel(const ushort* __restrict__ xbf, const ushort* __restrict__ aggw,
                            const float* __restrict__ agg_b, float* __restrict__ out,
                            float* __restrict__ psum, float* __restrict__ psumsq) {
    // XCD swizzle: xcd = lid%8 gets 112 consecutive gwids = 4 samples.
    const int lid  = blockIdx.x;
    const int gwid = (lid & 7) * 112 + (lid >> 3);
    const int b = gwid / 28;
    const int t = gwid - b * 28;          // h-tile 0..27
    const int h0 = t * 2;
    __shared__ ushort xs[4 * NPOS2 * 32]; // 59392 B

    const int tid  = threadIdx.x;
    const int lane = tid & 63;
    const int wid  = tid >> 6;
    const int wg = wid & 1;               // o base = wg*64
    const int kh = wid >> 1;              // channel half base = kh*64
    const int cf = lane & 15;
    const int kg = lane >> 4;

    // ---- staging: 3712 units (chunk, pos, quad); 15 strided per thread ----
    int sbyte[15]; const ushort* sga[15]; bool lv[15]; bool wv[15];
    #pragma unroll
    for (int u = 0; u < 15; ++u) {
        int un = tid + u * 256;
        wv[u] = un < 3712;
        int quad = un & 3;
        int rest = un >> 2;               // chunk*232 + pos
        int pos = rest % NPOS2;
        int chunk = rest / NPOS2;
        int row = pos / 58, col = pos - row * 58;
        int gh = h0 - 1 + row, gw = col - 1;
        lv[u] = wv[u] && gh >= 0 && gh < HH && gw >= 0 && gw < WW;
        int lin = un * 16;                // (chunk*232+pos)*64 + quad*16
        sbyte[u] = lin ^ ((pos & 7) << 4);
        sga[u] = xbf + ((size_t)((b * HH + gh) * WW + gw)) * CC + chunk * 32 + quad * 8;
    }

    // B-frag linear byte offsets (within chunk 0) + output offsets
    int blin[7], oofs[7];
    #pragma unroll
    for (int nf = 0; nf < 7; ++nf) {
        int p = nf * 16 + cf;
        int r = p / 56, w = p - r * 56;
        int pos = (r + 1) * 58 + (w + 1);
        blin[nf] = pos * 64 + kg * 16;
        oofs[nf] = (h0 + r) * WW + w;
    }

    const short8v zero8 = (short8v){0,0,0,0,0,0,0,0};
    {
        short8v sreg[15];
        #pragma unroll
        for (int u = 0; u < 15; ++u) {
            sreg[u] = zero8;
            if (lv[u]) sreg[u] = *(const short8v*)(sga[u]);
        }
        #pragma unroll
        for (int u = 0; u < 15; ++u)
            if (wv[u]) *(short8v*)((char*)xs + sbyte[u]) = sreg[u];
    }

    f32x4 acc[4][7];
    #pragma unroll
    for (int mf = 0; mf < 4; ++mf)
        #pragma unroll
        for (int nf = 0; nf < 7; ++nf) acc[mf][nf] = (f32x4){0.f, 0.f, 0.f, 0.f};

    // A: aggw[b][j][o][c]; this wave's K slice starts at kh*64
    const ushort* Abase = aggw + (size_t)b * 9 * 16384 + (size_t)(wg * 64 + cf) * 128
                        + kh * 64 + kg * 8;
    short8v pa[4];
    #pragma unroll
    for (int mf = 0; mf < 4; ++mf)
        pa[mf] = *(const short8v*)(Abase + mf * 2048);

    __syncthreads();

    // ---- barrier-free K-loop: 2 c-steps x 9 taps ----
    #pragma unroll
    for (int cs = 0; cs < 2; ++cs) {
        const int cbase = (kh * 2 + cs) * CHBYTES;
        #pragma unroll
        for (int j = 0; j < 9; ++j) {
            const int toff = ((j/3 - 1) * 58 + (j%3 - 1)) * 64;
            short8v ca[4];
            #pragma unroll
            for (int mf = 0; mf < 4; ++mf) ca[mf] = pa[mf];
            if (j < 8) {
                #pragma unroll
                for (int mf = 0; mf < 4; ++mf)
                    pa[mf] = *(const short8v*)(Abase + (size_t)(j+1) * 16384 + mf * 2048 + cs * 32);
            } else if (cs == 0) {
                #pragma unroll
                for (int mf = 0; mf < 4; ++mf)
                    pa[mf] = *(const short8v*)(Abase + mf * 2048 + 32);
            }
            #pragma unroll
            for (int nf = 0; nf < 7; ++nf) {
                int linb = cbase + blin[nf] + toff;
                int swz = linb ^ ((linb >> 2) & 0x70);
                short8v bf = *(const short8v*)((const char*)xs + swz);
                #pragma unroll
                for (int mf = 0; mf < 4; ++mf)
                    acc[mf][nf] = __builtin_amdgcn_mfma_f32_16x16x32_bf16(ca[mf], bf, acc[mf][nf], 0, 0, 0);
            }
        }
    }

    // ---- K-half reduction via LDS, then bias/store/stats (kh==0 waves) ----
    __syncthreads();
    float* red = (float*)xs;              // 2 * 64 * 116 floats = 59392 B
    if (kh == 1) {
        #pragma unroll
        for (int mf = 0; mf < 4; ++mf)
            #pragma unroll
            for (int i = 0; i < 4; ++i) {
                int ol = mf * 16 + kg * 4 + i;
                #pragma unroll
                for (int nf = 0; nf < 7; ++nf)
                    red[wg * 7424 + ol * 116 + nf * 16 + cf] = acc[mf][nf][i];
            }
    }
    __syncthreads();
    if (kh == 0) {
        #pragma unroll
        for (int mf = 0; mf < 4; ++mf) {
            #pragma unroll
            for (int i = 0; i < 4; ++i) {
                const int ol = mf * 16 + kg * 4 + i;
                const int o = wg * 64 + ol;
                const float ab = agg_b[b * OO + o];
                float* op = out + ((size_t)(b * OO + o)) * HW;
                float s = 0.f, s2 = 0.f;
                #pragma unroll
                for (int nf = 0; nf < 7; ++nf) {
                    float v = acc[mf][nf][i] + red[wg * 7424 + ol * 116 + nf * 16 + cf] + ab;
                    op[oofs[nf]] = v;
                    s += v; s2 += v * v;
                }
                s  += __shfl_xor(s, 1, 64);  s  += __shfl_xor(s, 2, 64);
                s  += __shfl_xor(s, 4, 64);  s  += __shfl_xor(s, 8, 64);
                s2 += __shfl_xor(s2, 1, 64); s2 += __shfl_xor(s2, 2, 64);
                s2 += __shfl_xor(s2, 4, 64); s2 += __shfl_xor(s2, 8, 64);
                if (cf == 0) {
                    psum[gwid * OO + o]   = s;
                    psumsq[gwid * OO + o] = s2;
                }
            }
        }
    }
}

// ---- final stats: one block per channel ----
__global__ void finstats_kernel(const float* __restrict__ psum, const float* __restrict__ psumsq,
                                float* __restrict__ sums, float* __restrict__ sumsq) {
    const int o = blockIdx.x, l = threadIdx.x;   // 64 threads
    float s = 0.f, s2 = 0.f;
    for (int r = l; r < 896; r += 64) { s += psum[r * OO + o]; s2 += psumsq[r * OO + o]; }
    for (int off = 32; off > 0; off >>= 1) {
        s  += __shfl_down(s, off, 64);
        s2 += __shfl_down(s2, off, 64);
    }
    if (l == 0) { sums[o] = s; sumsq[o] = s2; }
}

// ---- BN + ReLU in place ----
__global__ void bn_kernel(float* __restrict__ out,
                          const float* __restrict__ sums, const float* __restrict__ sumsq,
                          const float* __restrict__ gamma, const float* __restrict__ beta) {
    const float invN = 1.0f / (float)(BB * HW);
    const int total4 = BB * OO * HW / 4;
    for (int i = blockIdx.x * blockDim.x + threadIdx.x; i < total4; i += gridDim.x * blockDim.x) {
        int o = (i / (HW/4)) % OO;
        float mean = sums[o] * invN;
        float var  = sumsq[o] * invN - mean*mean;
        float inv  = rsqrtf(var + EPSV);
        float g  = gamma[o] * inv;
        float bt = beta[o] - mean * g;
        float4 v = ((float4*)out)[i];
        v.x = fmaxf(v.x*g + bt, 0.f);
        v.y = fmaxf(v.y*g + bt, 0.f);
        v.z = fmaxf(v.z*g + bt, 0.f);
        v.w = fmaxf(v.w*g + bt, 0.f);
        ((float4*)out)[i] = v;
    }
}

extern "C" void kernel_launch(void* const* d_in, const int* in_sizes, int n_in,
                              void* d_out, int out_size, void* d_ws, size_t ws_size,
                              hipStream_t stream) {
    const float* x      = (const float*)d_in[0];
    const float* fc1_w  = (const float*)d_in[1];
    const float* fc1_b  = (const float*)d_in[2];
    const float* fc2_w  = (const float*)d_in[3];
    const float* fc2_b  = (const float*)d_in[4];
    const float* weight = (const float*)d_in[5];
    const float* bias   = (const float*)d_in[6];
    const float* gamma  = (const float*)d_in[7];
    const float* beta   = (const float*)d_in[8];
    float* out = (float*)d_out;

    const size_t XBF_ELEMS  = (size_t)BB * HW * CC;        // 12,845,056
    const size_t AGGW_ELEMS = (size_t)BB * 9 * OO * CC;    //  4,718,592
    ushort* xbf  = (ushort*)d_ws;
    ushort* aggw = xbf + XBF_ELEMS;
    float*  wsf  = (float*)(aggw + AGGW_ELEMS);
    float* pooledp = wsf;                    // 229376
    float* attn    = pooledp + 229376;       // 128
    float* agg_b   = attn + 128;             // 4096
    float* psum    = agg_b + 4096;           // 114688 (896*128)
    float* psumsq  = psum + 114688;          // 114688
    float* sums    = psumsq + 114688;        // 128
    float* sumsq   = sums + 128;             // 128

    convert_pool_kernel<<<dim3(HH, BB), 256, 0, stream>>>(x, xbf, pooledp);
    attn_kernel<<<BB, 128, 0, stream>>>(pooledp, fc1_w, fc1_b, fc2_w, fc2_b, attn);
    aggw_kernel<<<(int)((AGGW_ELEMS + 255)/256), 256, 0, stream>>>(attn, weight, bias, aggw, agg_b);
    conv_kernel<<<dim3(896), 256, 0, stream>>>(xbf, aggw, agg_b, out, psum, psumsq);
    finstats_kernel<<<OO, 64, 0, stream>>>(psum, psumsq, sums, sumsq);
    bn_kernel<<<2048, 256, 0, stream>>>(out, sums, sumsq, gamma, beta);
}